// Round 1
// baseline (1669.400 us; speedup 1.0000x reference)
//
#include <hip/hip_runtime.h>

#define NB 65536
#define BLK 128

__device__ __forceinline__ float sigf(float x){ return 1.0f/(1.0f + __expf(-x)); }
__device__ __forceinline__ float tanh_fast(float x){ return 1.0f - 2.0f/(1.0f + __expf(2.0f*x)); }

// ---------------- Kernel 1: conv1+bn1+relu -> conv2+bn2+relu -> LIF1 -> LIF2 -> packed spikes + spatial_avg ----------
__global__ __launch_bounds__(BLK)
void k_conv_lif(const float* __restrict__ x,
                const float* __restrict__ c1w, const float* __restrict__ c1b,
                const float* __restrict__ b1g, const float* __restrict__ b1b,
                const float* __restrict__ b1m, const float* __restrict__ b1v,
                const float* __restrict__ c2w, const float* __restrict__ c2b,
                const float* __restrict__ b2g, const float* __restrict__ b2b,
                const float* __restrict__ b2m, const float* __restrict__ b2v,
                unsigned long long* __restrict__ spk,
                float* __restrict__ avg)
{
    // LIF membrane state: [channel][tid] -> lane-consecutive addresses, conflict-free
    __shared__ float mem1[33][BLK];
    __shared__ float mem2[33][BLK];
    const int tid = threadIdx.x;
    const int b = blockIdx.x * BLK + tid;

    #pragma unroll
    for (int k = 0; k < 33; ++k) { mem1[k][tid] = 0.f; mem2[k][tid] = 0.f; }

    // fold conv1 bias + bn1 into weights: h1 = relu(conv*s + t)
    float w1f[6][5], c1f[6];
    #pragma unroll
    for (int c = 0; c < 6; ++c) {
        float s = b1g[c] / sqrtf(b1v[c] + 1e-5f);
        #pragma unroll
        for (int j = 0; j < 5; ++j) w1f[c][j] = c1w[c*5+j] * s;
        c1f[c] = (c1b[c] - b1m[c]) * s + b1b[c];
    }
    // conv2 bn fold: h2 = relu(acc*s2v + t2v)
    float s2v[12], t2v[12];
    #pragma unroll
    for (int c = 0; c < 12; ++c) {
        float s = b2g[c] / sqrtf(b2v[c] + 1e-5f);
        s2v[c] = s;
        t2v[c] = (c2b[c] - b2m[c]) * s + b2b[c];
    }

    const float* xr = x + (size_t)b * 360;
    // rolling x window: xv[i] = x[4p-2+i], i=0..6
    float xv[7];
    xv[0] = 0.f; xv[1] = 0.f;
    #pragma unroll
    for (int i = 0; i < 5; ++i) xv[2+i] = xr[i];

    // rolling h1 columns: hA=col 2p-1, hB=col 2p, hC=col 2p+1 (post-relu; col -1 is zero pad)
    float hA[6], hB[6], hC[6];
    #pragma unroll
    for (int c = 0; c < 6; ++c) hA[c] = 0.f;

    float sum12[12];
    #pragma unroll
    for (int c = 0; c < 12; ++c) sum12[c] = 0.f;

    int kk = 0, tt = 0;            // uniform across lanes
    unsigned long long cur = 0ull; // 33 spike bits for current time step

    for (int p = 0; p < 90; ++p) {
        // conv1 cols 2p (xv[0..4]) and 2p+1 (xv[2..6])
        #pragma unroll
        for (int c = 0; c < 6; ++c) {
            float aB = c1f[c];
            float aC = c1f[c];
            #pragma unroll
            for (int j = 0; j < 5; ++j) { aB += w1f[c][j]*xv[j]; aC += w1f[c][j]*xv[j+2]; }
            hB[c] = fmaxf(aB, 0.f);
            hC[c] = fmaxf(aC, 0.f);
        }
        // conv2 at position p, 12 channels; flat order i = p*12 + c2 drives LIF channel kk = i % 33
        #pragma unroll
        for (int c2 = 0; c2 < 12; ++c2) {
            float acc = 0.f;
            #pragma unroll
            for (int c1 = 0; c1 < 6; ++c1) {
                const float* wp = c2w + c2*18 + c1*3;
                acc += wp[0]*hA[c1] + wp[1]*hB[c1] + wp[2]*hC[c1];
            }
            float hv = fmaxf(acc*s2v[c2] + t2v[c2], 0.f);
            sum12[c2] += hv;
            if (tt < 32) {   // only first 1056 flat elements feed the SNN
                float m1 = mem1[kk][tid];
                m1 = 0.95f*m1 + hv;
                float sp1 = (m1 > 0.5f) ? 1.f : 0.f;
                mem1[kk][tid] = m1 * (1.f - sp1);
                float m2 = mem2[kk][tid];
                m2 = 0.9f*m2 + sp1;
                bool sp2 = (m2 > 0.6f);
                mem2[kk][tid] = sp2 ? 0.f : m2;
                cur |= ((unsigned long long)(sp2 ? 1u : 0u)) << kk;
                if (++kk == 33) {
                    spk[(size_t)tt*NB + b] = cur;   // coalesced 8B store across lanes
                    cur = 0ull; kk = 0; ++tt;
                }
            }
        }
        // rotate h1 window and x window
        #pragma unroll
        for (int c = 0; c < 6; ++c) hA[c] = hC[c];
        xv[0] = xv[4]; xv[1] = xv[5]; xv[2] = xv[6];
        #pragma unroll
        for (int i = 0; i < 4; ++i) {
            int idx = 4*p + 5 + i;
            xv[3+i] = (idx < 360) ? xr[idx] : 0.f;
        }
    }
    #pragma unroll
    for (int c = 0; c < 12; ++c) avg[(size_t)c*NB + b] = sum12[c] / 90.0f;
}

// ---------------- Kernel 2: LSTM (32 steps) + attention head + fusion + classifier ----------------
__global__ __launch_bounds__(BLK)
void k_lstm_head(const unsigned long long* __restrict__ spk,
                 const float* __restrict__ avg,
                 const float* __restrict__ wih, const float* __restrict__ whh,
                 const float* __restrict__ bih, const float* __restrict__ bhh,
                 const float* __restrict__ rw1, const float* __restrict__ rb1,
                 const float* __restrict__ rw2, const float* __restrict__ rb2,
                 const float* __restrict__ fw,  const float* __restrict__ fb,
                 const float* __restrict__ cw1, const float* __restrict__ cb1,
                 const float* __restrict__ cw2, const float* __restrict__ cb2,
                 float* __restrict__ out)
{
    // c-state and h-next live in LDS because the j-loop index is runtime (avoids scratch spill).
    __shared__ float ccl[24][BLK];
    __shared__ float hnl[24][BLK];
    const int tid = threadIdx.x;
    const int b = blockIdx.x * BLK + tid;

    float h[24];
    #pragma unroll
    for (int j = 0; j < 24; ++j) { h[j] = 0.f; ccl[j][tid] = 0.f; }

    for (int t = 0; t < 32; ++t) {
        unsigned long long w = spk[(size_t)t*NB + b];   // coalesced
        float sv[33];
        #pragma unroll
        for (int k = 0; k < 33; ++k) sv[k] = ((w >> k) & 1ull) ? 1.f : 0.f;

        #pragma unroll 1   // keep body small: weights fetched via scalar loads each iter
        for (int j = 0; j < 24; ++j) {
            float gi = bih[j]      + bhh[j];
            float gf = bih[24+j]   + bhh[24+j];
            float gg = bih[48+j]   + bhh[48+j];
            float go = bih[72+j]   + bhh[72+j];
            const float* wi0 = wih + (j     )*33;
            const float* wi1 = wih + (24+j)*33;
            const float* wi2 = wih + (48+j)*33;
            const float* wi3 = wih + (72+j)*33;
            #pragma unroll
            for (int k = 0; k < 33; ++k) {
                float s = sv[k];
                gi += wi0[k]*s; gf += wi1[k]*s; gg += wi2[k]*s; go += wi3[k]*s;
            }
            const float* wh0 = whh + (j     )*24;
            const float* wh1 = whh + (24+j)*24;
            const float* wh2 = whh + (48+j)*24;
            const float* wh3 = whh + (72+j)*24;
            #pragma unroll
            for (int u = 0; u < 24; ++u) {
                float hv = h[u];
                gi += wh0[u]*hv; gf += wh1[u]*hv; gg += wh2[u]*hv; go += wh3[u]*hv;
            }
            float cprev = ccl[j][tid];
            float cn = sigf(gf)*cprev + sigf(gi)*tanh_fast(gg);
            ccl[j][tid] = cn;
            hnl[j][tid] = sigf(go)*tanh_fast(cn);
        }
        #pragma unroll
        for (int j = 0; j < 24; ++j) h[j] = hnl[j][tid];
    }

    float av[12];
    #pragma unroll
    for (int c = 0; c < 12; ++c) av[c] = avg[(size_t)c*NB + b];

    // attention head: relu(combined @ rw1^T + rb1) @ rw2^T + rb2 -> softmax
    float f1[12];
    #pragma unroll
    for (int r = 0; r < 12; ++r) {
        float a = rb1[r];
        #pragma unroll
        for (int u = 0; u < 24; ++u) a += rw1[r*36+u]*h[u];
        #pragma unroll
        for (int c = 0; c < 12; ++c) a += rw1[r*36+24+c]*av[c];
        f1[r] = fmaxf(a, 0.f);
    }
    float z0 = rb2[0], z1 = rb2[1];
    #pragma unroll
    for (int r = 0; r < 12; ++r) { z0 += rw2[r]*f1[r]; z1 += rw2[12+r]*f1[r]; }
    float mz = fmaxf(z0, z1);
    float e0 = __expf(z0 - mz), e1 = __expf(z1 - mz);
    float inv = 1.0f/(e0 + e1);
    float p0 = e0*inv, p1 = e1*inv;
    float r0 = 0.7f*p0, r1 = 0.3f*p1;
    float alpha = r0/(r0 + r1);

    float ha[24], sa[12];
    #pragma unroll
    for (int j = 0; j < 24; ++j) ha[j] = h[j]*alpha;
    #pragma unroll
    for (int c = 0; c < 12; ++c) sa[c] = av[c]*(1.f - alpha);

    float fu[24];
    #pragma unroll
    for (int r = 0; r < 24; ++r) {
        float a = fb[r];
        #pragma unroll
        for (int u = 0; u < 24; ++u) a += fw[r*36+u]*ha[u];
        #pragma unroll
        for (int c = 0; c < 12; ++c) a += fw[r*36+24+c]*sa[c];
        fu[r] = fmaxf(a, 0.f);
    }
    float c1o[12];
    #pragma unroll
    for (int r = 0; r < 12; ++r) {
        float a = cb1[r];
        #pragma unroll
        for (int u = 0; u < 24; ++u) a += cw1[r*24+u]*fu[u];
        c1o[r] = fmaxf(a, 0.f);
    }
    #pragma unroll
    for (int o = 0; o < 5; ++o) {
        float a = cb2[o];
        #pragma unroll
        for (int r = 0; r < 12; ++r) a += cw2[o*12+r]*c1o[r];
        out[(size_t)b*5 + o] = a;
    }
}

extern "C" void kernel_launch(void* const* d_in, const int* in_sizes, int n_in,
                              void* d_out, int out_size, void* d_ws, size_t ws_size,
                              hipStream_t stream) {
    const float* x    = (const float*)d_in[0];
    const float* c1w  = (const float*)d_in[1];
    const float* c1b  = (const float*)d_in[2];
    const float* b1g  = (const float*)d_in[3];
    const float* b1b  = (const float*)d_in[4];
    const float* b1m  = (const float*)d_in[5];
    const float* b1v  = (const float*)d_in[6];
    const float* c2w  = (const float*)d_in[7];
    const float* c2b  = (const float*)d_in[8];
    const float* b2g  = (const float*)d_in[9];
    const float* b2b  = (const float*)d_in[10];
    const float* b2m  = (const float*)d_in[11];
    const float* b2v  = (const float*)d_in[12];
    const float* wih  = (const float*)d_in[13];
    const float* whh  = (const float*)d_in[14];
    const float* bih  = (const float*)d_in[15];
    const float* bhh  = (const float*)d_in[16];
    const float* rw1  = (const float*)d_in[17];
    const float* rb1  = (const float*)d_in[18];
    const float* rw2  = (const float*)d_in[19];
    const float* rb2  = (const float*)d_in[20];
    const float* fw   = (const float*)d_in[21];
    const float* fb   = (const float*)d_in[22];
    const float* cw1  = (const float*)d_in[23];
    const float* cb1  = (const float*)d_in[24];
    const float* cw2  = (const float*)d_in[25];
    const float* cb2  = (const float*)d_in[26];
    float* out = (float*)d_out;

    unsigned long long* spk = (unsigned long long*)d_ws;                 // 32*NB*8 = 16.78 MB
    float* avg = (float*)((char*)d_ws + (size_t)32*NB*sizeof(unsigned long long)); // 12*NB*4 = 3.15 MB

    dim3 grid(NB/BLK), blk(BLK);
    k_conv_lif<<<grid, blk, 0, stream>>>(x, c1w, c1b, b1g, b1b, b1m, b1v,
                                         c2w, c2b, b2g, b2b, b2m, b2v, spk, avg);
    k_lstm_head<<<grid, blk, 0, stream>>>(spk, avg, wih, whh, bih, bhh,
                                          rw1, rb1, rw2, rb2, fw, fb,
                                          cw1, cb1, cw2, cb2, out);
}

// Round 2
// 1358.905 us; speedup vs baseline: 1.2285x; 1.2285x over previous
//
#include <hip/hip_runtime.h>

#define NB 65536
#define BLK 128
#define LBLK 256

__device__ __forceinline__ float sigf(float x){ return 1.0f/(1.0f + __expf(-x)); }
__device__ __forceinline__ float tanh_fast(float x){ return 1.0f - 2.0f/(1.0f + __expf(2.0f*x)); }

// ---------------- Kernel 1: conv1+bn1+relu -> conv2+bn2+relu -> LIF1 -> LIF2 -> packed spikes + spatial_avg ----------
// Thread-per-sample. x is read via chunked float4 prefetch: 8 independent 16B loads issued
// per 6-position chunk, one wait, instead of ~24 serialized scalar loads.
__global__ __launch_bounds__(BLK)
void k_conv_lif(const float* __restrict__ x,
                const float* __restrict__ c1w, const float* __restrict__ c1b,
                const float* __restrict__ b1g, const float* __restrict__ b1b,
                const float* __restrict__ b1m, const float* __restrict__ b1v,
                const float* __restrict__ c2w, const float* __restrict__ c2b,
                const float* __restrict__ b2g, const float* __restrict__ b2b,
                const float* __restrict__ b2m, const float* __restrict__ b2v,
                unsigned long long* __restrict__ spk,
                float* __restrict__ avg)
{
    __shared__ float mem1[33][BLK];
    __shared__ float mem2[33][BLK];
    const int tid = threadIdx.x;
    const int b = blockIdx.x * BLK + tid;

    #pragma unroll
    for (int k = 0; k < 33; ++k) { mem1[k][tid] = 0.f; mem2[k][tid] = 0.f; }

    // fold conv1 bias + bn1 into weights
    float w1f[6][5], c1f[6];
    #pragma unroll
    for (int c = 0; c < 6; ++c) {
        float s = b1g[c] / sqrtf(b1v[c] + 1e-5f);
        #pragma unroll
        for (int j = 0; j < 5; ++j) w1f[c][j] = c1w[c*5+j] * s;
        c1f[c] = (c1b[c] - b1m[c]) * s + b1b[c];
    }
    float s2v[12], t2v[12];
    #pragma unroll
    for (int c = 0; c < 12; ++c) {
        float s = b2g[c] / sqrtf(b2v[c] + 1e-5f);
        s2v[c] = s;
        t2v[c] = (c2b[c] - b2m[c]) * s + b2b[c];
    }

    const float* xr = x + (size_t)b * 360;

    float hA[6];
    #pragma unroll
    for (int c = 0; c < 6; ++c) hA[c] = 0.f;
    float hB[6], hC[6];

    float sum12[12];
    #pragma unroll
    for (int c = 0; c < 12; ++c) sum12[c] = 0.f;

    int kk = 0, tt = 0;            // uniform across lanes
    unsigned long long cur = 0ull;

    for (int cch = 0; cch < 15; ++cch) {     // 15 chunks x 6 positions = 90
        // prefetch x[24*cch-4 .. 24*cch+28) as 8 float4s (independent, one wait)
        float4 buf[8];
        const int gbase0 = 24*cch - 4;
        #pragma unroll
        for (int e = 0; e < 8; ++e) {
            int gi = gbase0 + 4*e;
            if (gi >= 0 && gi < 360) buf[e] = *(const float4*)(xr + gi);
            else                     buf[e] = make_float4(0.f,0.f,0.f,0.f);
        }
        #pragma unroll
        for (int q = 0; q < 6; ++q) {
            // window x[4p-2 .. 4p+4], p = 6*cch+q  -> rel floats [4q+2 .. 4q+8]
            const float xv0 = buf[q].z,   xv1 = buf[q].w,
                        xv2 = buf[q+1].x, xv3 = buf[q+1].y,
                        xv4 = buf[q+1].z, xv5 = buf[q+1].w,
                        xv6 = buf[q+2].x;
            #pragma unroll
            for (int c = 0; c < 6; ++c) {
                float aB = c1f[c] + w1f[c][0]*xv0 + w1f[c][1]*xv1 + w1f[c][2]*xv2
                                  + w1f[c][3]*xv3 + w1f[c][4]*xv4;
                float aC = c1f[c] + w1f[c][0]*xv2 + w1f[c][1]*xv3 + w1f[c][2]*xv4
                                  + w1f[c][3]*xv5 + w1f[c][4]*xv6;
                hB[c] = fmaxf(aB, 0.f);
                hC[c] = fmaxf(aC, 0.f);
            }
            #pragma unroll
            for (int c2 = 0; c2 < 12; ++c2) {
                float acc = 0.f;
                #pragma unroll
                for (int c1 = 0; c1 < 6; ++c1) {
                    const float* wp = c2w + c2*18 + c1*3;
                    acc += wp[0]*hA[c1] + wp[1]*hB[c1] + wp[2]*hC[c1];
                }
                float hv = fmaxf(acc*s2v[c2] + t2v[c2], 0.f);
                sum12[c2] += hv;
                if (tt < 32) {
                    float m1 = mem1[kk][tid];
                    m1 = 0.95f*m1 + hv;
                    float sp1 = (m1 > 0.5f) ? 1.f : 0.f;
                    mem1[kk][tid] = m1 * (1.f - sp1);
                    float m2 = mem2[kk][tid];
                    m2 = 0.9f*m2 + sp1;
                    bool sp2 = (m2 > 0.6f);
                    mem2[kk][tid] = sp2 ? 0.f : m2;
                    cur |= ((unsigned long long)(sp2 ? 1u : 0u)) << kk;
                    if (++kk == 33) {
                        spk[(size_t)tt*NB + b] = cur;
                        cur = 0ull; kk = 0; ++tt;
                    }
                }
            }
            #pragma unroll
            for (int c = 0; c < 6; ++c) hA[c] = hC[c];
        }
    }
    #pragma unroll
    for (int c = 0; c < 12; ++c) avg[(size_t)c*NB + b] = sum12[c] / 90.0f;
}

// ---------------- Kernel 2: LSTM (32 steps) + heads ----------------
// 256-thread block = 4 waves handle 64 samples. Wave `sub` owns hidden units
// j in [6*sub, 6*sub+6). h exchanged per step through LDS (conflict-free layout),
// c stays in registers. Weight rows are wave-uniform (readfirstlane) -> scalar loads.
// 4096 waves total -> ~4 waves/SIMD occupancy.
__global__ __launch_bounds__(LBLK, 4)
void k_lstm_head(const unsigned long long* __restrict__ spk,
                 const float* __restrict__ avg,
                 const float* __restrict__ wih, const float* __restrict__ whh,
                 const float* __restrict__ bih, const float* __restrict__ bhh,
                 const float* __restrict__ rw1, const float* __restrict__ rb1,
                 const float* __restrict__ rw2, const float* __restrict__ rb2,
                 const float* __restrict__ fw,  const float* __restrict__ fb,
                 const float* __restrict__ cw1, const float* __restrict__ cb1,
                 const float* __restrict__ cw2, const float* __restrict__ cb2,
                 float* __restrict__ out)
{
    __shared__ float hsh[24][64];
    const int tid  = threadIdx.x;
    const int lane = tid & 63;
    const int sub  = __builtin_amdgcn_readfirstlane(tid >> 6);  // 0..3, SGPR
    const int jbase = sub * 6;
    const int b = blockIdx.x * 64 + lane;

    float c[6];
    #pragma unroll
    for (int jl = 0; jl < 6; ++jl) { c[jl] = 0.f; hsh[jbase+jl][lane] = 0.f; }

    // wave-uniform bias sums, kept in regs
    float bs0[6], bs1[6], bs2[6], bs3[6];
    #pragma unroll
    for (int jl = 0; jl < 6; ++jl) {
        int j = jbase + jl;
        bs0[jl] = bih[j]    + bhh[j];
        bs1[jl] = bih[24+j] + bhh[24+j];
        bs2[jl] = bih[48+j] + bhh[48+j];
        bs3[jl] = bih[72+j] + bhh[72+j];
    }
    __syncthreads();

    for (int t = 0; t < 32; ++t) {
        const unsigned long long w = spk[(size_t)t*NB + (size_t)blockIdx.x*64 + lane];
        float sv[33];
        #pragma unroll
        for (int k = 0; k < 33; ++k) sv[k] = ((w >> k) & 1ull) ? 1.f : 0.f;

        float hr[24];
        #pragma unroll
        for (int u = 0; u < 24; ++u) hr[u] = hsh[u][lane];   // conflict-free broadcast rows
        __syncthreads();   // all reads of old h done

        #pragma unroll
        for (int jl = 0; jl < 6; ++jl) {
            const int j = jbase + jl;
            float gi = bs0[jl], gf = bs1[jl], gg = bs2[jl], go = bs3[jl];
            const float* wi0 = wih + j*33;
            const float* wi1 = wih + (24+j)*33;
            const float* wi2 = wih + (48+j)*33;
            const float* wi3 = wih + (72+j)*33;
            #pragma unroll
            for (int k = 0; k < 33; ++k) {
                const float s = sv[k];
                gi += wi0[k]*s; gf += wi1[k]*s; gg += wi2[k]*s; go += wi3[k]*s;
            }
            const float* wh0 = whh + j*24;
            const float* wh1 = whh + (24+j)*24;
            const float* wh2 = whh + (48+j)*24;
            const float* wh3 = whh + (72+j)*24;
            #pragma unroll
            for (int u = 0; u < 24; ++u) {
                const float hv = hr[u];
                gi += wh0[u]*hv; gf += wh1[u]*hv; gg += wh2[u]*hv; go += wh3[u]*hv;
            }
            const float cn = sigf(gf)*c[jl] + sigf(gi)*tanh_fast(gg);
            c[jl] = cn;
            hsh[j][lane] = sigf(go)*tanh_fast(cn);
        }
        __syncthreads();   // new h visible
    }

    if (sub == 0) {        // one wave finishes the heads for its 64 samples
        float h[24];
        #pragma unroll
        for (int u = 0; u < 24; ++u) h[u] = hsh[u][lane];
        float av[12];
        #pragma unroll
        for (int cc = 0; cc < 12; ++cc) av[cc] = avg[(size_t)cc*NB + b];

        float f1[12];
        #pragma unroll
        for (int r = 0; r < 12; ++r) {
            float a = rb1[r];
            #pragma unroll
            for (int u = 0; u < 24; ++u) a += rw1[r*36+u]*h[u];
            #pragma unroll
            for (int cc = 0; cc < 12; ++cc) a += rw1[r*36+24+cc]*av[cc];
            f1[r] = fmaxf(a, 0.f);
        }
        float z0 = rb2[0], z1 = rb2[1];
        #pragma unroll
        for (int r = 0; r < 12; ++r) { z0 += rw2[r]*f1[r]; z1 += rw2[12+r]*f1[r]; }
        float mz = fmaxf(z0, z1);
        float e0 = __expf(z0 - mz), e1 = __expf(z1 - mz);
        float inv = 1.0f/(e0 + e1);
        float r0 = 0.7f*e0*inv, r1 = 0.3f*e1*inv;
        float alpha = r0/(r0 + r1);

        float ha[24], sa[12];
        #pragma unroll
        for (int u = 0; u < 24; ++u) ha[u] = h[u]*alpha;
        #pragma unroll
        for (int cc = 0; cc < 12; ++cc) sa[cc] = av[cc]*(1.f - alpha);

        float fu[24];
        #pragma unroll
        for (int r = 0; r < 24; ++r) {
            float a = fb[r];
            #pragma unroll
            for (int u = 0; u < 24; ++u) a += fw[r*36+u]*ha[u];
            #pragma unroll
            for (int cc = 0; cc < 12; ++cc) a += fw[r*36+24+cc]*sa[cc];
            fu[r] = fmaxf(a, 0.f);
        }
        float c1o[12];
        #pragma unroll
        for (int r = 0; r < 12; ++r) {
            float a = cb1[r];
            #pragma unroll
            for (int u = 0; u < 24; ++u) a += cw1[r*24+u]*fu[u];
            c1o[r] = fmaxf(a, 0.f);
        }
        #pragma unroll
        for (int o = 0; o < 5; ++o) {
            float a = cb2[o];
            #pragma unroll
            for (int r = 0; r < 12; ++r) a += cw2[o*12+r]*c1o[r];
            out[(size_t)b*5 + o] = a;
        }
    }
}

extern "C" void kernel_launch(void* const* d_in, const int* in_sizes, int n_in,
                              void* d_out, int out_size, void* d_ws, size_t ws_size,
                              hipStream_t stream) {
    const float* x    = (const float*)d_in[0];
    const float* c1w  = (const float*)d_in[1];
    const float* c1b  = (const float*)d_in[2];
    const float* b1g  = (const float*)d_in[3];
    const float* b1b  = (const float*)d_in[4];
    const float* b1m  = (const float*)d_in[5];
    const float* b1v  = (const float*)d_in[6];
    const float* c2w  = (const float*)d_in[7];
    const float* c2b  = (const float*)d_in[8];
    const float* b2g  = (const float*)d_in[9];
    const float* b2b  = (const float*)d_in[10];
    const float* b2m  = (const float*)d_in[11];
    const float* b2v  = (const float*)d_in[12];
    const float* wih  = (const float*)d_in[13];
    const float* whh  = (const float*)d_in[14];
    const float* bih  = (const float*)d_in[15];
    const float* bhh  = (const float*)d_in[16];
    const float* rw1  = (const float*)d_in[17];
    const float* rb1  = (const float*)d_in[18];
    const float* rw2  = (const float*)d_in[19];
    const float* rb2  = (const float*)d_in[20];
    const float* fw   = (const float*)d_in[21];
    const float* fb   = (const float*)d_in[22];
    const float* cw1  = (const float*)d_in[23];
    const float* cb1  = (const float*)d_in[24];
    const float* cw2  = (const float*)d_in[25];
    const float* cb2  = (const float*)d_in[26];
    float* out = (float*)d_out;

    unsigned long long* spk = (unsigned long long*)d_ws;                 // 16.78 MB
    float* avg = (float*)((char*)d_ws + (size_t)32*NB*sizeof(unsigned long long)); // 3.15 MB

    k_conv_lif<<<dim3(NB/BLK), dim3(BLK), 0, stream>>>(x, c1w, c1b, b1g, b1b, b1m, b1v,
                                                       c2w, c2b, b2g, b2b, b2m, b2v, spk, avg);
    k_lstm_head<<<dim3(NB/64), dim3(LBLK), 0, stream>>>(spk, avg, wih, whh, bih, bhh,
                                                        rw1, rb1, rw2, rb2, fw, fb,
                                                        cw1, cb1, cw2, cb2, out);
}

// Round 3
// 519.492 us; speedup vs baseline: 3.2135x; 2.6158x over previous
//
#include <hip/hip_runtime.h>

#define NB 65536
#define CBLK 256

typedef unsigned long long u64;
typedef __attribute__((ext_vector_type(8))) short short8;   // 8 bf16 (guide-verified typing)
typedef __attribute__((ext_vector_type(4))) float f32x4;

union FragAB { unsigned short us[8]; unsigned w[4]; short8 v; };

__device__ __forceinline__ float sigf(float x){ return 1.0f/(1.0f + __expf(-x)); }
__device__ __forceinline__ float tanh_fast(float x){ return 1.0f - 2.0f/(1.0f + __expf(2.0f*x)); }

__device__ __forceinline__ unsigned short f2bf(float f){
    union { float f; unsigned u; } x; x.f = f;
    unsigned r = x.u + 0x7FFFu + ((x.u >> 16) & 1u);   // RNE
    return (unsigned short)(r >> 16);
}
__device__ __forceinline__ float bf2f(unsigned short h){
    union { unsigned u; float f; } x; x.u = ((unsigned)h) << 16; return x.f;
}

// ============ Kernel 1: conv1+bn1+relu -> conv2+bn2+relu -> LIF1 -> LIF2 (registers!) ============
// Thread per sample. Superstep = 11 positions = 132 sites = exactly 4 LIF time-steps,
// so kk = site%33 and c2 = site%12 are compile-time constants -> mem1/mem2 in VGPRs, zero LDS.
__global__ __launch_bounds__(CBLK)
void k_conv_lif(const float* __restrict__ x,
                const float* __restrict__ c1w, const float* __restrict__ c1b,
                const float* __restrict__ b1g, const float* __restrict__ b1b,
                const float* __restrict__ b1m, const float* __restrict__ b1v,
                const float* __restrict__ c2w, const float* __restrict__ c2b,
                const float* __restrict__ b2g, const float* __restrict__ b2b,
                const float* __restrict__ b2m, const float* __restrict__ b2v,
                u64* __restrict__ spk,
                float* __restrict__ avg)
{
    const int b = blockIdx.x * CBLK + threadIdx.x;
    const float* xr = x + (size_t)b * 360;

    float w1f[6][5], c1f[6];
    #pragma unroll
    for (int c = 0; c < 6; ++c) {
        float s = b1g[c] / sqrtf(b1v[c] + 1e-5f);
        #pragma unroll
        for (int j = 0; j < 5; ++j) w1f[c][j] = c1w[c*5+j] * s;
        c1f[c] = (c1b[c] - b1m[c]) * s + b1b[c];
    }
    float s2v[12], t2v[12];
    #pragma unroll
    for (int c = 0; c < 12; ++c) {
        float s = b2g[c] / sqrtf(b2v[c] + 1e-5f);
        s2v[c] = s;
        t2v[c] = (c2b[c] - b2m[c]) * s + b2b[c];
    }

    float m1[33], m2[33];
    #pragma unroll
    for (int k = 0; k < 33; ++k) { m1[k] = 0.f; m2[k] = 0.f; }

    float sum12[12];
    #pragma unroll
    for (int c = 0; c < 12; ++c) sum12[c] = 0.f;

    float hA[6], hB[6], hC[6];
    #pragma unroll
    for (int c = 0; c < 6; ++c) hA[c] = 0.f;

    #pragma unroll 1
    for (int ss = 0; ss < 8; ++ss) {
        // x window for positions p = 11ss .. 11ss+10: x[44ss-4 .. 44ss+47], 13 aligned float4
        float xw[52];
        #pragma unroll
        for (int e = 0; e < 13; ++e) {
            int gi = 44*ss - 4 + 4*e;
            float4 v;
            if (gi >= 0) v = *(const float4*)(xr + gi);   // max gi=352 -> reads x[352..355], in range
            else         v = make_float4(0.f, 0.f, 0.f, 0.f);
            xw[4*e+0] = v.x; xw[4*e+1] = v.y; xw[4*e+2] = v.z; xw[4*e+3] = v.w;
        }

        unsigned curlo = 0u, curhi = 0u;
        #pragma unroll
        for (int pi = 0; pi < 11; ++pi) {
            const float xv0 = xw[4*pi+2], xv1 = xw[4*pi+3], xv2 = xw[4*pi+4],
                        xv3 = xw[4*pi+5], xv4 = xw[4*pi+6], xv5 = xw[4*pi+7],
                        xv6 = xw[4*pi+8];
            #pragma unroll
            for (int c = 0; c < 6; ++c) {
                float aB = c1f[c] + w1f[c][0]*xv0 + w1f[c][1]*xv1 + w1f[c][2]*xv2
                                  + w1f[c][3]*xv3 + w1f[c][4]*xv4;
                float aC = c1f[c] + w1f[c][0]*xv2 + w1f[c][1]*xv3 + w1f[c][2]*xv4
                                  + w1f[c][3]*xv5 + w1f[c][4]*xv6;
                hB[c] = fmaxf(aB, 0.f);
                hC[c] = fmaxf(aC, 0.f);
            }
            #pragma unroll
            for (int c2 = 0; c2 < 12; ++c2) {
                float acc = 0.f;
                #pragma unroll
                for (int c1 = 0; c1 < 6; ++c1) {
                    const float* wp = c2w + c2*18 + c1*3;
                    acc += wp[0]*hA[c1] + wp[1]*hB[c1] + wp[2]*hC[c1];
                }
                float hv = fmaxf(acc*s2v[c2] + t2v[c2], 0.f);
                sum12[c2] += hv;

                const int ls = 12*pi + c2;       // 0..131, compile-time
                const int kk = ls % 33;          // compile-time
                float v1 = 0.95f*m1[kk] + hv;
                float sp1 = (v1 > 0.5f) ? 1.f : 0.f;
                m1[kk] = v1 * (1.f - sp1);
                float v2 = 0.9f*m2[kk] + sp1;
                bool sp2 = (v2 > 0.6f);
                m2[kk] = sp2 ? 0.f : v2;
                if (sp2) { if (kk < 32) curlo |= (1u << kk); else curhi |= 1u; }
                if (kk == 32) {
                    spk[(size_t)(4*ss + ls/33)*NB + b] = ((u64)curhi << 32) | (u64)curlo;
                    curlo = 0u; curhi = 0u;
                }
            }
            #pragma unroll
            for (int c = 0; c < 6; ++c) hA[c] = hC[c];
        }
    }

    // tail positions 88, 89 (feed avg only)
    {
        float xw2[13];
        float4 a0 = *(const float4*)(xr + 348);
        float4 a1 = *(const float4*)(xr + 352);
        float4 a2 = *(const float4*)(xr + 356);
        xw2[0]=a0.x; xw2[1]=a0.y; xw2[2]=a0.z; xw2[3]=a0.w;
        xw2[4]=a1.x; xw2[5]=a1.y; xw2[6]=a1.z; xw2[7]=a1.w;
        xw2[8]=a2.x; xw2[9]=a2.y; xw2[10]=a2.z; xw2[11]=a2.w;
        xw2[12]=0.f;
        #pragma unroll
        for (int pt = 0; pt < 2; ++pt) {
            const float xv0 = xw2[2+4*pt], xv1 = xw2[3+4*pt], xv2 = xw2[4+4*pt],
                        xv3 = xw2[5+4*pt], xv4 = xw2[6+4*pt], xv5 = xw2[7+4*pt],
                        xv6 = xw2[8+4*pt];
            #pragma unroll
            for (int c = 0; c < 6; ++c) {
                float aB = c1f[c] + w1f[c][0]*xv0 + w1f[c][1]*xv1 + w1f[c][2]*xv2
                                  + w1f[c][3]*xv3 + w1f[c][4]*xv4;
                float aC = c1f[c] + w1f[c][0]*xv2 + w1f[c][1]*xv3 + w1f[c][2]*xv4
                                  + w1f[c][3]*xv5 + w1f[c][4]*xv6;
                hB[c] = fmaxf(aB, 0.f);
                hC[c] = fmaxf(aC, 0.f);
            }
            #pragma unroll
            for (int c2 = 0; c2 < 12; ++c2) {
                float acc = 0.f;
                #pragma unroll
                for (int c1 = 0; c1 < 6; ++c1) {
                    const float* wp = c2w + c2*18 + c1*3;
                    acc += wp[0]*hA[c1] + wp[1]*hB[c1] + wp[2]*hC[c1];
                }
                sum12[c2] += fmaxf(acc*s2v[c2] + t2v[c2], 0.f);
            }
            #pragma unroll
            for (int c = 0; c < 6; ++c) hA[c] = hC[c];
        }
    }
    #pragma unroll
    for (int c = 0; c < 12; ++c) avg[(size_t)c*NB + b] = sum12[c] / 90.0f;
}

// ============ Kernel 2: MFMA LSTM (split-bf16) + heads ============
// Block = 4 independent waves; wave handles 16 samples. A = reordered weights (rows 4u+gate)
// resident in VGPRs as bf16 hi/lo splits; B = spikes (exact bf16) / h hi+lo splits.
// C-layout: lane holds gates i,f,g,o of unit 4m+q (q=lane>>4) for sample col=lane&15.
__global__ __launch_bounds__(256, 2)
void k_lstm_mfma(const u64* __restrict__ spk,
                 const float* __restrict__ avg,
                 const float* __restrict__ wih, const float* __restrict__ whh,
                 const float* __restrict__ bih, const float* __restrict__ bhh,
                 const float* __restrict__ rw1, const float* __restrict__ rb1,
                 const float* __restrict__ rw2, const float* __restrict__ rb2,
                 const float* __restrict__ fw,  const float* __restrict__ fb,
                 const float* __restrict__ cw1, const float* __restrict__ cb1,
                 const float* __restrict__ cw2, const float* __restrict__ cb2,
                 float* __restrict__ out)
{
    __shared__ unsigned short hx[4][16][64];  // per wave: [n][0..23]=h_hi, [32..55]=h_lo, rest 0
    __shared__ float hf[4][16][24];           // final h fp32 for heads

    const int tid  = threadIdx.x;
    const int lane = tid & 63;
    const int wv   = __builtin_amdgcn_readfirstlane(tid >> 6);
    const int q    = lane >> 4;       // k-slice group (A and B) / row-quad (C)
    const int n16  = lane & 15;       // sample col (B/C) ; row-in-tile (A)
    const int sample = blockIdx.x * 64 + wv * 16 + n16;

    // zero this wave's hx region (also serves as h(t=-1)=0 and the K-pad zeros)
    {
        unsigned* zp = (unsigned*)&hx[wv][0][0];
        #pragma unroll
        for (int i = 0; i < 8; ++i) zp[lane + 64*i] = 0u;
    }

    // ---- load A fragments (weights), one-time ----
    short8 WihHi[6][2], WihLo[6], WhhHi[6], WhhLo[6];
    #pragma unroll
    for (int m = 0; m < 6; ++m) {
        const int rowA = 16*m + n16;           // A-layout: row = lane&15
        const int u    = rowA >> 2;
        const int gt   = rowA & 3;
        const float* wr = wih + (gt*24 + u)*33;
        FragAB fh, fl;
        #pragma unroll
        for (int j = 0; j < 8; ++j) {
            float v = wr[q*8 + j];             // k = q*8+j, all < 32 valid
            unsigned short h = f2bf(v);
            fh.us[j] = h;
            fl.us[j] = f2bf(v - bf2f(h));
        }
        WihHi[m][0] = fh.v; WihLo[m] = fl.v;
        FragAB f1;
        #pragma unroll
        for (int j = 0; j < 8; ++j) f1.us[j] = 0;
        if (q == 0) f1.us[0] = f2bf(wr[32]);   // k=32 (hi only; lo term ~1e-5 at out, dropped)
        WihHi[m][1] = f1.v;

        const float* hr = whh + (gt*24 + u)*24;
        FragAB gh, gl;
        #pragma unroll
        for (int j = 0; j < 8; ++j) {
            int k = q*8 + j;
            float v = (k < 24) ? hr[k] : 0.f;
            unsigned short h = f2bf(v);
            gh.us[j] = h;
            gl.us[j] = (k < 24) ? f2bf(v - bf2f(h)) : (unsigned short)0;
        }
        WhhHi[m] = gh.v; WhhLo[m] = gl.v;
    }

    // biases: lane's rows are 16m+4q+rr -> unit 4m+q, gate rr
    float bias[6][4];
    #pragma unroll
    for (int m = 0; m < 6; ++m) {
        const int u = 4*m + q;
        #pragma unroll
        for (int rr = 0; rr < 4; ++rr)
            bias[m][rr] = bih[rr*24 + u] + bhh[rr*24 + u];
    }

    float cst[6], hreg[6];
    #pragma unroll
    for (int m = 0; m < 6; ++m) { cst[m] = 0.f; hreg[m] = 0.f; }

    const u64* sp = spk + sample;
    u64 wcur = sp[0];
    const int q8 = q * 8;

    __asm__ volatile("s_waitcnt lgkmcnt(0)" ::: "memory");   // hx zero visible to own wave

    #pragma unroll 1
    for (int t = 0; t < 32; ++t) {
        // B fragments for h (state t-1; zeros at t=0 via init)
        short8 BhHi = *reinterpret_cast<const short8*>(&hx[wv][n16][q8]);
        short8 BhLo = *reinterpret_cast<const short8*>(&hx[wv][n16][32 + q8]);

        // B fragments for spikes (exact bf16 0/1)
        const unsigned lo32 = (unsigned)wcur;
        const unsigned hi32 = (unsigned)(wcur >> 32);
        FragAB bs0;
        {
            const unsigned byt = (lo32 >> q8) & 0xFFu;
            #pragma unroll
            for (int p = 0; p < 4; ++p) {
                unsigned e0 = (byt >> (2*p)) & 1u;
                unsigned e1 = (byt >> (2*p+1)) & 1u;
                bs0.w[p] = (e0 ? 0x3F80u : 0u) | (e1 ? 0x3F800000u : 0u);
            }
        }
        FragAB bs1;
        bs1.w[0] = (q == 0 && (hi32 & 1u)) ? 0x3F80u : 0u;
        bs1.w[1] = 0u; bs1.w[2] = 0u; bs1.w[3] = 0u;

        // prefetch next spike word early
        u64 wnext = 0;
        if (t < 31) wnext = sp[(size_t)(t+1)*NB];

        // gates = bias + Wih*spk + Whh*h  (split-bf16)
        f32x4 acc[6];
        #pragma unroll
        for (int m = 0; m < 6; ++m) {
            f32x4 a; a[0]=bias[m][0]; a[1]=bias[m][1]; a[2]=bias[m][2]; a[3]=bias[m][3];
            a = __builtin_amdgcn_mfma_f32_16x16x32_bf16(WihHi[m][0], bs0.v, a, 0, 0, 0);
            a = __builtin_amdgcn_mfma_f32_16x16x32_bf16(WihLo[m],    bs0.v, a, 0, 0, 0);
            a = __builtin_amdgcn_mfma_f32_16x16x32_bf16(WihHi[m][1], bs1.v, a, 0, 0, 0);
            a = __builtin_amdgcn_mfma_f32_16x16x32_bf16(WhhHi[m],    BhHi,  a, 0, 0, 0);
            a = __builtin_amdgcn_mfma_f32_16x16x32_bf16(WhhLo[m],    BhHi,  a, 0, 0, 0);
            a = __builtin_amdgcn_mfma_f32_16x16x32_bf16(WhhHi[m],    BhLo,  a, 0, 0, 0);
            acc[m] = a;
        }

        // epilogue: lane-local LSTM cell for units 4m+q of its sample
        #pragma unroll
        for (int m = 0; m < 6; ++m) {
            float ii = sigf(acc[m][0]);
            float ff = sigf(acc[m][1]);
            float gg = tanh_fast(acc[m][2]);
            float oo = sigf(acc[m][3]);
            float cn = ff*cst[m] + ii*gg;
            cst[m] = cn;
            float h = oo * tanh_fast(cn);
            hreg[m] = h;
            unsigned short hh = f2bf(h);
            unsigned short hl = f2bf(h - bf2f(hh));
            hx[wv][n16][4*m + q]      = hh;
            hx[wv][n16][32 + 4*m + q] = hl;
        }
        __asm__ volatile("s_waitcnt lgkmcnt(0)" ::: "memory");  // intra-wave ds RAW
        wcur = wnext;
    }

    // publish final h (fp32) for the head phase
    #pragma unroll
    for (int m = 0; m < 6; ++m) hf[wv][n16][4*m + q] = hreg[m];
    __asm__ volatile("s_waitcnt lgkmcnt(0)" ::: "memory");

    if (lane < 16) {
        const int sm = lane;
        const int bidx = blockIdx.x * 64 + wv * 16 + sm;
        float h[24];
        #pragma unroll
        for (int u2 = 0; u2 < 24; ++u2) h[u2] = hf[wv][sm][u2];
        float av[12];
        #pragma unroll
        for (int cc = 0; cc < 12; ++cc) av[cc] = avg[(size_t)cc*NB + bidx];

        float f1[12];
        #pragma unroll
        for (int r = 0; r < 12; ++r) {
            float a = rb1[r];
            #pragma unroll
            for (int u2 = 0; u2 < 24; ++u2) a += rw1[r*36+u2]*h[u2];
            #pragma unroll
            for (int cc = 0; cc < 12; ++cc) a += rw1[r*36+24+cc]*av[cc];
            f1[r] = fmaxf(a, 0.f);
        }
        float z0 = rb2[0], z1 = rb2[1];
        #pragma unroll
        for (int r = 0; r < 12; ++r) { z0 += rw2[r]*f1[r]; z1 += rw2[12+r]*f1[r]; }
        float mz = fmaxf(z0, z1);
        float e0 = __expf(z0 - mz), e1 = __expf(z1 - mz);
        float inv = 1.0f/(e0 + e1);
        float r0 = 0.7f*e0*inv, r1 = 0.3f*e1*inv;
        float alpha = r0/(r0 + r1);

        float ha[24], sa[12];
        #pragma unroll
        for (int u2 = 0; u2 < 24; ++u2) ha[u2] = h[u2]*alpha;
        #pragma unroll
        for (int cc = 0; cc < 12; ++cc) sa[cc] = av[cc]*(1.f - alpha);

        float fu[24];
        #pragma unroll
        for (int r = 0; r < 24; ++r) {
            float a = fb[r];
            #pragma unroll
            for (int u2 = 0; u2 < 24; ++u2) a += fw[r*36+u2]*ha[u2];
            #pragma unroll
            for (int cc = 0; cc < 12; ++cc) a += fw[r*36+24+cc]*sa[cc];
            fu[r] = fmaxf(a, 0.f);
        }
        float c1o[12];
        #pragma unroll
        for (int r = 0; r < 12; ++r) {
            float a = cb1[r];
            #pragma unroll
            for (int u2 = 0; u2 < 24; ++u2) a += cw1[r*24+u2]*fu[u2];
            c1o[r] = fmaxf(a, 0.f);
        }
        #pragma unroll
        for (int o = 0; o < 5; ++o) {
            float a = cb2[o];
            #pragma unroll
            for (int r = 0; r < 12; ++r) a += cw2[o*12+r]*c1o[r];
            out[(size_t)bidx*5 + o] = a;
        }
    }
}

extern "C" void kernel_launch(void* const* d_in, const int* in_sizes, int n_in,
                              void* d_out, int out_size, void* d_ws, size_t ws_size,
                              hipStream_t stream) {
    const float* x    = (const float*)d_in[0];
    const float* c1w  = (const float*)d_in[1];
    const float* c1b  = (const float*)d_in[2];
    const float* b1g  = (const float*)d_in[3];
    const float* b1b  = (const float*)d_in[4];
    const float* b1m  = (const float*)d_in[5];
    const float* b1v  = (const float*)d_in[6];
    const float* c2w  = (const float*)d_in[7];
    const float* c2b  = (const float*)d_in[8];
    const float* b2g  = (const float*)d_in[9];
    const float* b2b  = (const float*)d_in[10];
    const float* b2m  = (const float*)d_in[11];
    const float* b2v  = (const float*)d_in[12];
    const float* wih  = (const float*)d_in[13];
    const float* whh  = (const float*)d_in[14];
    const float* bih  = (const float*)d_in[15];
    const float* bhh  = (const float*)d_in[16];
    const float* rw1  = (const float*)d_in[17];
    const float* rb1  = (const float*)d_in[18];
    const float* rw2  = (const float*)d_in[19];
    const float* rb2  = (const float*)d_in[20];
    const float* fw   = (const float*)d_in[21];
    const float* fb   = (const float*)d_in[22];
    const float* cw1  = (const float*)d_in[23];
    const float* cb1  = (const float*)d_in[24];
    const float* cw2  = (const float*)d_in[25];
    const float* cb2  = (const float*)d_in[26];
    float* out = (float*)d_out;

    u64* spk  = (u64*)d_ws;                                            // 16.78 MB
    float* avg = (float*)((char*)d_ws + (size_t)32*NB*sizeof(u64));    // 3.15 MB

    k_conv_lif<<<dim3(NB/CBLK), dim3(CBLK), 0, stream>>>(x, c1w, c1b, b1g, b1b, b1m, b1v,
                                                         c2w, c2b, b2g, b2b, b2m, b2v, spk, avg);
    k_lstm_mfma<<<dim3(NB/64), dim3(256), 0, stream>>>(spk, avg, wih, whh, bih, bhh,
                                                       rw1, rb1, rw2, rb2, fw, fb,
                                                       cw1, cb1, cw2, cb2, out);
}